// Round 15
// baseline (190.796 us; speedup 1.0000x reference)
//
#include <hip/hip_runtime.h>
#include <hip/hip_bf16.h>

typedef unsigned short u16;
typedef unsigned int u32;
typedef __attribute__((ext_vector_type(8))) __bf16 bf16x8;
typedef __attribute__((ext_vector_type(4))) float f32x4;

// dims
#define Bd  2048
#define Nd  768
#define Md  8192
#define Ed  512
#define Hd  8
#define NSL 8          // m-slices for ctx partials
#define AIT 16         // iters per attn_sc block = (Md/NSL)/64

__device__ __forceinline__ u16 f2bf(float f){
    union { __bf16 b; u16 u; } c; c.b = (__bf16)f; return c.u;
}
__device__ __forceinline__ float bf2f(u16 u){
    union { unsigned u; float f; } a; a.u = ((unsigned)u)<<16; return a.f;
}
__device__ __forceinline__ u32 pack2(float a, float b){
    union { ushort2 s; u32 u; } r;
    r.s.x = f2bf(a); r.s.y = f2bf(b);
    return r.u;
}
__device__ __forceinline__ float fexp2(float x){ return __builtin_amdgcn_exp2f(x); }

__device__ __forceinline__ void glds16(const void* g, void* l){
    __builtin_amdgcn_global_load_lds((const __attribute__((address_space(1))) void*)g,
                                     (__attribute__((address_space(3))) void*)l, 16, 0, 0);
}

// ================= prep kernel: conversions + transposes + gemv + zero =================
struct CvtSeg { const float* src; u16* dst; float* dstf; int n4; };
struct PrepArgs {
    CvtSeg s[9]; int total4;
    const float* Wv; u16* WvT;         // 768x768 transpose
    const float* ow; u16* owT;         // 512x512 transpose
    const float* Wo; const float* ob; const float* Wob; float* bo;
    float* sume;
};
#define PREP_CVT_BLKS 10320
#define TCVT0_BLKS 576
#define TCVT1_BLKS 256
#define GEMV_BLKS 192
#define ZERO_BLKS 16

__global__ __launch_bounds__(256, 8)
void prep_k(PrepArgs a){
    __shared__ float t[32][33];
    const int bid = blockIdx.x, tid = threadIdx.x;
    if (bid < PREP_CVT_BLKS){
        int i = bid*256 + tid;
        if (i >= a.total4) return;
        #pragma unroll
        for (int k=0;k<9;k++){
            if (i < a.s[k].n4){
                float4 v = *(const float4*)(a.s[k].src + (size_t)i*4);
                if (a.s[k].dstf) *(float4*)(a.s[k].dstf + (size_t)i*4) = v;
                ushort4 u; u.x=f2bf(v.x); u.y=f2bf(v.y); u.z=f2bf(v.z); u.w=f2bf(v.w);
                *(ushort4*)(a.s[k].dst + (size_t)i*4) = u;
                return;
            }
            i -= a.s[k].n4;
        }
        return;
    }
    int local = bid - PREP_CVT_BLKS;
    if (local < TCVT0_BLKS + TCVT1_BLKS){
        const float* in; u16* out; int R, bx, by;
        if (local < TCVT0_BLKS){ in=a.Wv; out=a.WvT; R=Nd; bx=local%24; by=local/24; }
        else { int l2=local-TCVT0_BLKS; in=a.ow; out=a.owT; R=Ed; bx=l2%16; by=l2/16; }
        const int tx = tid & 31, ty = tid >> 5;
        const int r0 = by*32, c0 = bx*32;
        #pragma unroll
        for (int i=0;i<4;i++)
            t[ty + i*8][tx] = in[(size_t)(r0+ty+i*8)*R + c0+tx];
        __syncthreads();
        #pragma unroll
        for (int i=0;i<4;i++)
            out[(size_t)(c0+ty+i*8)*R + r0+tx] = f2bf(t[tx][ty+i*8]);
        return;
    }
    local -= TCVT0_BLKS + TCVT1_BLKS;
    if (local < GEMV_BLKS){
        const int wave = tid >> 6, lane = tid & 63;
        const int i = local*4 + wave;
        float s = 0.f;
        for (int j = lane; j < 512; j += 64) s += a.Wo[(size_t)i*512 + j] * a.ob[j];
        #pragma unroll
        for (int off = 32; off; off >>= 1) s += __shfl_down(s, off);
        if (lane == 0) a.bo[i] = s + a.Wob[i];
        return;
    }
    local -= GEMV_BLKS;
    {
        int idx = local*1024 + tid*4;
        *(float4*)(a.sume + idx) = make_float4(0.f,0.f,0.f,0.f);
    }
}

// ================= batched GEMM: C[M,N] = alpha*A[M,K]@B[N,K]^T (+bias*bscale) =================
struct GSeg {
    const u16* A; const u16* B; void* C; const float* bias;
    int M, N, K; float alpha, bscale; int biasmode, outf32, blk0, nbx;
};
struct GBatch { GSeg s[5]; int nseg; };

__global__ __launch_bounds__(256, 3)
void gemm_multi(GBatch gb)
{
    __shared__ u16 lA[128*64];
    __shared__ u16 lB[128*64];
    const int bid = blockIdx.x;
    int si = 0;
    #pragma unroll
    for (int k=1;k<5;k++) if (k < gb.nseg && bid >= gb.s[k].blk0) si = k;
    const GSeg sg = gb.s[si];
    const int local = bid - sg.blk0;
    const int bx = local % sg.nbx, by = local / sg.nbx;
    const int K = sg.K, N = sg.N;

    const int tid = threadIdx.x;
    const int wave = tid >> 6, lane = tid & 63;
    const int wr = wave >> 1, wc = wave & 1;
    const size_t row0 = (size_t)by * 128;
    const size_t col0 = (size_t)bx * 128;

    f32x4 acc[4][4] = {};

    const int srow = wave*32 + (lane>>3);
    const int scol = (lane&7)*8;
    const u16* gA = sg.A + (row0 + srow)*(size_t)K + scol;
    const u16* gB = sg.B + (col0 + srow)*(size_t)K + scol;

    for (int kt = 0; kt < K; kt += 64) {
        #pragma unroll
        for (int i = 0; i < 4; ++i) {
            glds16(gA + (size_t)i*8*K + kt, lA + (wave*32 + i*8)*64);
            glds16(gB + (size_t)i*8*K + kt, lB + (wave*32 + i*8)*64);
        }
        __syncthreads();
        #pragma unroll
        for (int ks = 0; ks < 2; ++ks) {
            bf16x8 af[4], bfv[4];
            #pragma unroll
            for (int i = 0; i < 4; ++i)
                af[i] = *(const bf16x8*)&lA[(wr*64 + i*16 + (lane&15))*64 + ks*32 + (lane>>4)*8];
            #pragma unroll
            for (int i = 0; i < 4; ++i)
                bfv[i] = *(const bf16x8*)&lB[(wc*64 + i*16 + (lane&15))*64 + ks*32 + (lane>>4)*8];
            #pragma unroll
            for (int mi = 0; mi < 4; ++mi)
                #pragma unroll
                for (int ni = 0; ni < 4; ++ni)
                    acc[mi][ni] = __builtin_amdgcn_mfma_f32_16x16x32_bf16(af[mi], bfv[ni], acc[mi][ni], 0, 0, 0);
        }
        __syncthreads();
    }

    #pragma unroll
    for (int mi = 0; mi < 4; ++mi) {
        #pragma unroll
        for (int j = 0; j < 4; ++j) {
            const size_t r = row0 + wr*64 + mi*16 + (lane>>4)*4 + j;
            float badd_r = (sg.biasmode==2) ? sg.bias[r]*sg.bscale : 0.f;
            #pragma unroll
            for (int ni = 0; ni < 4; ++ni) {
                const size_t c = col0 + wc*64 + ni*16 + (lane&15);
                float bv = (sg.biasmode==1) ? sg.bias[c]*sg.bscale : badd_r;
                float v = acc[mi][ni][j] * sg.alpha + bv;
                if (sg.outf32) ((float*)sg.C)[r*(size_t)N + c] = v;
                else           ((u16*)sg.C)[r*(size_t)N + c] = f2bf(v);
            }
        }
    }
}

// ================= fused attention: sumexp + unnormalized ctx partials =================
__global__ __launch_bounds__(256, 2)
void attn_sc(const u16* __restrict__ qp, const u16* __restrict__ kp,
             const u16* __restrict__ vTp, float* __restrict__ sumexp,
             u16* __restrict__ part)
{
    __shared__ u16 lK[2][64*64];
    __shared__ u16 lV[2][64*64];
    __shared__ u16 lP[4][64*64];
    const int tid = threadIdx.x, w = tid>>6, l = tid&63;
    const int g = l>>4, b15 = l&15;
    const int h = blockIdx.x & 7;
    const int rest = blockIdx.x >> 3;
    const int msl = rest & (NSL-1), bt = rest >> 3;
    const int m0 = msl * (AIT*64);

    bf16x8 qf[4][2];
    #pragma unroll
    for (int rt=0; rt<4; ++rt)
        #pragma unroll
        for (int ks=0; ks<2; ++ks)
            qf[rt][ks] = *(const bf16x8*)&qp[(size_t)(bt*256 + w*64 + rt*16 + b15)*512
                                            + h*64 + ks*32 + g*8];

    int addrW[4][4], addrR[4][2];
    #pragma unroll
    for (int rt=0; rt<4; ++rt){
        int bl = rt*16 + b15;
        #pragma unroll
        for (int ct=0; ct<4; ++ct){
            int chunk = ct*2 + (g>>1);
            addrW[rt][ct] = bl*128 + ((chunk ^ (bl&7))<<4) + (g&1)*8;
        }
        #pragma unroll
        for (int ks2=0; ks2<2; ++ks2)
            addrR[rt][ks2] = bl*128 + (((ks2*4+g) ^ (bl&7))<<4);
    }

    const int srcc = ((l&7) ^ (l>>3))*8;
    char* lPw = (char*)lP[w];

    auto STAGE = [&](int buf, int mb){
        #pragma unroll
        for (int i=0;i<2;i++)
            glds16(kp + (size_t)(mb + w*16 + i*8 + (l>>3))*512 + h*64 + srcc,
                   &lK[buf][(w*16 + i*8)*64]);
        #pragma unroll
        for (int i=0;i<2;i++)
            glds16(vTp + (size_t)(h*64 + w*16 + i*8 + (l>>3))*8192 + mb + srcc,
                   &lV[buf][(w*16 + i*8)*64]);
    };

    STAGE(0, m0);
    __syncthreads();

    f32x4 cacc[4][4] = {};
    float rs[4] = {};
    int cur = 0;
    for (int t=0; t<AIT; ++t){
        if (t+1 < AIT) STAGE(cur^1, m0 + (t+1)*64);

        f32x4 sacc[4][4] = {};
        #pragma unroll
        for (int ks=0; ks<2; ++ks){
            bf16x8 bk[4];
            #pragma unroll
            for (int ct=0; ct<4; ++ct)
                bk[ct] = *(const bf16x8*)&lK[cur][(ct*16+b15)*64 + (((ks*4+g) ^ (b15&7))<<3)];
            #pragma unroll
            for (int rt=0; rt<4; ++rt)
                #pragma unroll
                for (int ct=0; ct<4; ++ct)
                    sacc[rt][ct] = __builtin_amdgcn_mfma_f32_16x16x32_bf16(bk[ct], qf[rt][ks], sacc[rt][ct],0,0,0);
        }
        #pragma unroll
        for (int rt=0; rt<4; ++rt)
            #pragma unroll
            for (int ct=0; ct<4; ++ct){
                float p0 = fexp2(sacc[rt][ct][0]);
                float p1 = fexp2(sacc[rt][ct][1]);
                float p2 = fexp2(sacc[rt][ct][2]);
                float p3 = fexp2(sacc[rt][ct][3]);
                rs[rt] += (p0+p1)+(p2+p3);
                uint2 pk; pk.x = pack2(p0,p1); pk.y = pack2(p2,p3);
                *(uint2*)(lPw + addrW[rt][ct]) = pk;
            }
        #pragma unroll
        for (int ks2=0; ks2<2; ++ks2){
            bf16x8 vb[4];
            #pragma unroll
            for (int ai=0; ai<4; ++ai)
                vb[ai] = *(const bf16x8*)&lV[cur][(ai*16+b15)*64 + (((ks2*4+g) ^ (b15&7))<<3)];
            #pragma unroll
            for (int rt=0; rt<4; ++rt){
                bf16x8 pa = *(const bf16x8*)(lPw + addrR[rt][ks2]);
                #pragma unroll
                for (int ai=0; ai<4; ++ai)
                    cacc[rt][ai] = __builtin_amdgcn_mfma_f32_16x16x32_bf16(pa, vb[ai], cacc[rt][ai],0,0,0);
            }
        }
        __syncthreads();
        cur ^= 1;
    }

    #pragma unroll
    for (int rt=0; rt<4; ++rt)
        #pragma unroll
        for (int ai=0; ai<4; ++ai)
            #pragma unroll
            for (int j=0; j<4; ++j){
                size_t r = (size_t)bt*256 + w*64 + rt*16 + g*4 + j;
                size_t c = (size_t)h*64 + ai*16 + b15;
                part[((size_t)msl<<20) + r*512 + c] = f2bf(cacc[rt][ai][j]);
            }
    #pragma unroll
    for (int rt=0; rt<4; ++rt){
        float s = rs[rt];
        s += __shfl_xor(s, 16); s += __shfl_xor(s, 32);
        if (l < 16)
            atomicAdd(&sumexp[h*2048 + bt*256 + w*64 + rt*16 + l], s);
    }
}

// ctx[b,e] = (sum_msl part[msl][b][e]) / sumexp[h(e), b]
__global__ void ctx_reduce_k(const u16* __restrict__ part, const float* __restrict__ sume,
                             u16* __restrict__ ctx){
    int i = (blockIdx.x*256 + threadIdx.x)*4;
    int b = i >> 9, h = (i >> 6) & 7;
    float ri = 1.0f / sume[h*2048 + b];
    float s0=0.f, s1=0.f, s2=0.f, s3=0.f;
    #pragma unroll
    for (int k=0;k<NSL;k++){
        ushort4 v = *(const ushort4*)(part + ((size_t)k<<20) + i);
        s0 += bf2f(v.x); s1 += bf2f(v.y); s2 += bf2f(v.z); s3 += bf2f(v.w);
    }
    ushort4 u;
    u.x = f2bf(s0*ri); u.y = f2bf(s1*ri); u.z = f2bf(s2*ri); u.w = f2bf(s3*ri);
    *(ushort4*)(ctx + i) = u;
}

// ================= final merged kernel: epilogue GEMM (96 blocks) + attn_f (1024 blocks) =================
// attn_f v3: all-8-heads K in 64KB LDS (one barrier total), h as RUNTIME loop
// (#pragma unroll 1) so live ranges stay one-iteration wide (no spill, cf. R9/R10).
struct FinArgs {
    const u16* ctxb; const u16* Woo2T; const float* bo; float* out_xhat;
    const u16* qp; const u16* kp; const float* sume; float* fo;
};
#define EPB 96

__global__ __launch_bounds__(256, 2)
void fin_k(FinArgs fa)
{
    __shared__ char smem[73728];   // 72 KB
    const int tid = threadIdx.x;

    if (blockIdx.x < EPB){
        // ---- epilogue GEMM: out_xhat[2048,768] = ctxb[2048,512] @ Woo2T[768,512]^T + bo ----
        u16* lA = (u16*)smem;             // 128*64
        u16* lB = (u16*)(smem + 16384);   // 128*64
        const int local = blockIdx.x;
        const int bx = local % 6, by = local / 6;
        const int K = Ed, N = Nd;
        const int wave = tid >> 6, lane = tid & 63;
        const int wr = wave >> 1, wc = wave & 1;
        const size_t row0 = (size_t)by * 128;
        const size_t col0 = (size_t)bx * 128;
        f32x4 acc[4][4] = {};
        const int srow = wave*32 + (lane>>3);
        const int scol = (lane&7)*8;
        const u16* gA = fa.ctxb + (row0 + srow)*(size_t)K + scol;
        const u16* gB = fa.Woo2T + (col0 + srow)*(size_t)K + scol;
        for (int kt = 0; kt < K; kt += 64) {
            #pragma unroll
            for (int i = 0; i < 4; ++i) {
                glds16(gA + (size_t)i*8*K + kt, lA + (wave*32 + i*8)*64);
                glds16(gB + (size_t)i*8*K + kt, lB + (wave*32 + i*8)*64);
            }
            __syncthreads();
            #pragma unroll
            for (int ks = 0; ks < 2; ++ks) {
                bf16x8 af[4], bfv[4];
                #pragma unroll
                for (int i = 0; i < 4; ++i)
                    af[i] = *(const bf16x8*)&lA[(wr*64 + i*16 + (lane&15))*64 + ks*32 + (lane>>4)*8];
                #pragma unroll
                for (int i = 0; i < 4; ++i)
                    bfv[i] = *(const bf16x8*)&lB[(wc*64 + i*16 + (lane&15))*64 + ks*32 + (lane>>4)*8];
                #pragma unroll
                for (int mi = 0; mi < 4; ++mi)
                    #pragma unroll
                    for (int ni = 0; ni < 4; ++ni)
                        acc[mi][ni] = __builtin_amdgcn_mfma_f32_16x16x32_bf16(af[mi], bfv[ni], acc[mi][ni], 0, 0, 0);
            }
            __syncthreads();
        }
        #pragma unroll
        for (int mi = 0; mi < 4; ++mi)
            #pragma unroll
            for (int j = 0; j < 4; ++j) {
                const size_t r = row0 + wr*64 + mi*16 + (lane>>4)*4 + j;
                #pragma unroll
                for (int ni = 0; ni < 4; ++ni) {
                    const size_t c = col0 + wc*64 + ni*16 + (lane&15);
                    fa.out_xhat[r*(size_t)N + c] = acc[mi][ni][j] + fa.bo[c];
                }
            }
        return;
    }

    // ---- attn_f: f[b,m] = sum_h exp2(q.k) * 0.125/sumexp[h,b] ----
    u16* lK = (u16*)smem;                    // [64 rows][512 cols] swizzled (64 KB)
    float* lR = (float*)(smem + 65536);      // [8*256] (8 KB)
    const int w = tid>>6, l = tid&63;
    const int g = l>>4, b15 = l&15;
    const int bid = blockIdx.x - EPB;
    const int xcd = bid & 7, r2 = bid >> 3;
    const int mt = xcd*16 + (r2 & 15), bt = r2 >> 4;  // mt 0..127, bt 0..7

    #pragma unroll
    for (int i=0;i<8;i++){
        int id = i*256 + tid;
        lR[id] = 0.125f / fa.sume[(id>>8)*2048 + bt*256 + (id&255)];
    }
    // stage all 8 heads: 64 rows x 512 bf16; one glds16 stages one full row.
    // LDS chunk p of row r holds global chunk (p&56)|((p^r)&7)  [16B chunks]
    #pragma unroll
    for (int i=0;i<16;i++){
        int row = w*16 + i;
        int sc = (l & 56) | ((l ^ row) & 7);
        glds16(fa.kp + (size_t)(mt*64 + row)*512 + sc*8, lK + row*512);
    }
    __syncthreads();

    f32x4 facc[4][4] = {};
    const u16* qbase = fa.qp + (size_t)(bt*256 + w*64 + b15)*512 + g*8;

    #pragma unroll 1
    for (int h=0; h<8; ++h){
        bf16x8 qf[4][2];
        #pragma unroll
        for (int rt=0; rt<4; ++rt)
            #pragma unroll
            for (int ks=0; ks<2; ++ks)
                qf[rt][ks] = *(const bf16x8*)&qbase[(size_t)(rt*16)*512 + h*64 + ks*32];
        #pragma unroll
        for (int ch=0; ch<2; ++ch){
            f32x4 sacc[4][2] = {};
            #pragma unroll
            for (int ks=0; ks<2; ++ks){
                bf16x8 bk[2];
                #pragma unroll
                for (int c2=0; c2<2; ++c2){
                    int rb = (ch*2+c2)*16 + b15;
                    int chunk = h*8 + (((ks*4+g) ^ (rb&7)));
                    bk[c2] = *(const bf16x8*)&lK[rb*512 + chunk*8];
                }
                #pragma unroll
                for (int rt=0; rt<4; ++rt)
                    #pragma unroll
                    for (int c2=0; c2<2; ++c2)
                        sacc[rt][c2] = __builtin_amdgcn_mfma_f32_16x16x32_bf16(bk[c2], qf[rt][ks], sacc[rt][c2],0,0,0);
            }
            #pragma unroll
            for (int rt=0; rt<4; ++rt){
                float ri = lR[h*256 + w*64 + rt*16 + b15];
                #pragma unroll
                for (int c2=0; c2<2; ++c2)
                    #pragma unroll
                    for (int j=0;j<4;j++)
                        facc[rt][ch*2+c2][j] += fexp2(sacc[rt][c2][j]) * ri;
            }
        }
        __builtin_amdgcn_sched_barrier(0);
    }
    #pragma unroll
    for (int rt=0; rt<4; ++rt){
        size_t b = (size_t)bt*256 + w*64 + rt*16 + b15;
        #pragma unroll
        for (int ct=0; ct<4; ++ct)
            *(float4*)&fa.fo[b*8192 + mt*64 + ct*16 + g*4] = *(float4*)&facc[rt][ct];
    }
}

// ------------------------------------------------------------------
extern "C" void kernel_launch(void* const* d_in, const int* in_sizes, int n_in,
                              void* d_out, int out_size, void* d_ws, size_t ws_size,
                              hipStream_t stream)
{
    const float* x   = (const float*)d_in[0];
    const float* Xc  = (const float*)d_in[1];
    const float* Wq  = (const float*)d_in[2];
    const float* Wk  = (const float*)d_in[3];
    const float* Wv  = (const float*)d_in[4];
    const float* qw  = (const float*)d_in[5];
    const float* kw  = (const float*)d_in[6];
    const float* vw  = (const float*)d_in[7];
    const float* bq  = (const float*)d_in[8];
    const float* bk  = (const float*)d_in[9];
    const float* bv  = (const float*)d_in[10];
    const float* ow  = (const float*)d_in[11];
    const float* ob  = (const float*)d_in[12];
    const float* Wo  = (const float*)d_in[13];
    const float* Wob = (const float*)d_in[14];

    float* out_x    = (float*)d_out;
    float* out_xhat = out_x + (size_t)Bd*Nd;
    float* out_f    = out_xhat + (size_t)Bd*Nd;
    float* out_V    = out_f + (size_t)Bd*Md;

    char* wsb = (char*)d_ws;
    size_t off = 0;
    auto alloc = [&](size_t bytes) -> void* {
        void* p = wsb + off; off += (bytes + 255) & ~(size_t)255; return p;
    };
    u16* xb     = (u16*)alloc((size_t)Bd*Nd*2);
    u16* Xb     = (u16*)alloc((size_t)Md*Nd*2);
    u16* qwb    = (u16*)alloc((size_t)Ed*Ed*2);
    u16* kwb    = (u16*)alloc((size_t)Ed*Ed*2);
    u16* vwb    = (u16*)alloc((size_t)Ed*Nd*2);
    u16* Wqb    = (u16*)alloc((size_t)Nd*Ed*2);
    u16* Wkb    = (u16*)alloc((size_t)Nd*Ed*2);
    u16* Wvb    = (u16*)alloc((size_t)Nd*Nd*2);
    u16* WvTb   = (u16*)alloc((size_t)Nd*Nd*2);
    u16* Wo_b   = (u16*)alloc((size_t)Nd*Ed*2);
    u16* owTb   = (u16*)alloc((size_t)Ed*Ed*2);
    u16* WqqT   = (u16*)alloc((size_t)Ed*Nd*2);
    u16* WkkT   = (u16*)alloc((size_t)Ed*Nd*2);
    u16* WvvT   = (u16*)alloc((size_t)Ed*Nd*2);
    u16* Woo2T  = (u16*)alloc((size_t)Nd*Ed*2);
    float* bo   = (float*)alloc((size_t)Nd*4);
    u16* qb     = (u16*)alloc((size_t)Bd*Ed*2);
    u16* kb     = (u16*)alloc((size_t)Md*Ed*2);
    u16* vTb    = (u16*)alloc((size_t)Ed*Md*2);
    u16* ctxb   = (u16*)alloc((size_t)Bd*Ed*2);
    float* sume = (float*)alloc((size_t)Hd*Bd*4);
    u16* part   = (u16*)alloc((size_t)NSL*Bd*Ed*2);
    if (off > ws_size) return;

    const float LOG2E = 1.44269504f;

    // ---- launch 1: prep ----
    PrepArgs pa;
    pa.s[0] = { x,  xb,  out_x,   Bd*Nd/4 };
    pa.s[1] = { Xc, Xb,  nullptr, Md*Nd/4 };
    pa.s[2] = { qw, qwb, nullptr, Ed*Ed/4 };
    pa.s[3] = { kw, kwb, nullptr, Ed*Ed/4 };
    pa.s[4] = { vw, vwb, nullptr, Ed*Nd/4 };
    pa.s[5] = { Wq, Wqb, nullptr, Nd*Ed/4 };
    pa.s[6] = { Wk, Wkb, nullptr, Nd*Ed/4 };
    pa.s[7] = { Wv, Wvb, nullptr, Nd*Nd/4 };
    pa.s[8] = { Wo, Wo_b, nullptr, Nd*Ed/4 };
    pa.total4 = (Bd*Nd + Md*Nd + Ed*Ed*2 + Ed*Nd + Nd*Ed*2 + Nd*Nd + Nd*Ed)/4;
    pa.Wv = Wv; pa.WvT = WvTb; pa.ow = ow; pa.owT = owTb;
    pa.Wo = Wo; pa.ob = ob; pa.Wob = Wob; pa.bo = bo;
    pa.sume = sume;
    prep_k<<<PREP_CVT_BLKS + TCVT0_BLKS + TCVT1_BLKS + GEMV_BLKS + ZERO_BLKS, 256, 0, stream>>>(pa);

    // ---- launch 2: batch1 = 4 weight combines ONLY (96 blocks, short) ----
    {
        GBatch gb; gb.nseg = 4;
        gb.s[0] = { qwb, Wqb, WqqT, nullptr, Ed, Nd, Ed, 0.125f*0.125f*LOG2E, 1.f, 0, 0,   0, Nd/128 };
        gb.s[1] = { kwb, Wkb, WkkT, nullptr, Ed, Nd, Ed, 1.f, 1.f, 0, 0,  24, Nd/128 };
        gb.s[2] = { vwb, Wvb, WvvT, nullptr, Ed, Nd, Nd, 1.f, 1.f, 0, 0,  48, Nd/128 };
        gb.s[3] = { Wo_b, owTb, Woo2T, nullptr, Nd, Ed, Ed, 1.f, 1.f, 0, 0,  72, Ed/128 };
        gb.s[4] = gb.s[0];
        gemm_multi<<<96, 256, 0, stream>>>(gb);
    }
    // ---- launch 3: batch2 = V + k + vT + q projections (960 blocks, well packed) ----
    {
        GBatch gb; gb.nseg = 4;
        gb.s[0] = { Xb, WvTb, out_V, nullptr, Md, Nd, Nd, 1.f, 1.f, 0, 1,   0, Nd/128 };          // V (f32 out), 384 blocks
        gb.s[1] = { Xb, WkkT, kb, bk, Md, Ed, Nd, 1.f, 1.f, 1, 0, 384, Ed/128 };                  // k, 256 blocks
        gb.s[2] = { WvvT, Xb, vTb, bv, Ed, Md, Nd, 1.f, 1.f, 2, 0, 640, Md/128 };                 // vT, 256 blocks
        gb.s[3] = { xb, WqqT, qb, bq, Bd, Ed, Nd, 1.f, 0.125f*LOG2E, 1, 0, 896, Ed/128 };         // q, 64 blocks
        gb.s[4] = gb.s[0];
        gemm_multi<<<960, 256, 0, stream>>>(gb);
    }

    // ---- launch 4: fused attention (sumexp + ctx partials) ----
    attn_sc<<<512, 256, 0, stream>>>(qb, kb, vTb, sume, part);
    // ---- launch 5: ctx reduce ----
    ctx_reduce_k<<<Bd*Ed/1024, 256, 0, stream>>>(part, sume, ctxb);
    // ---- launch 6: merged epilogue GEMM + attn_f ----
    FinArgs fa = { ctxb, Woo2T, bo, out_xhat, qb, kb, sume, out_f };
    fin_k<<<EPB + 1024, 256, 0, stream>>>(fa);
}

// Round 16
// 178.191 us; speedup vs baseline: 1.0707x; 1.0707x over previous
//
#include <hip/hip_runtime.h>
#include <hip/hip_bf16.h>

typedef unsigned short u16;
typedef unsigned int u32;
typedef __attribute__((ext_vector_type(8))) __bf16 bf16x8;
typedef __attribute__((ext_vector_type(4))) float f32x4;

// dims
#define Bd  2048
#define Nd  768
#define Md  8192
#define Ed  512
#define Hd  8
#define NSL 8          // m-slices for ctx partials
#define AIT 16         // iters per attn_sc block = (Md/NSL)/64

__device__ __forceinline__ u16 f2bf(float f){
    union { __bf16 b; u16 u; } c; c.b = (__bf16)f; return c.u;
}
__device__ __forceinline__ float bf2f(u16 u){
    union { unsigned u; float f; } a; a.u = ((unsigned)u)<<16; return a.f;
}
__device__ __forceinline__ u32 pack2(float a, float b){
    union { ushort2 s; u32 u; } r;
    r.s.x = f2bf(a); r.s.y = f2bf(b);
    return r.u;
}
__device__ __forceinline__ float fexp2(float x){ return __builtin_amdgcn_exp2f(x); }

__device__ __forceinline__ void glds16(const void* g, void* l){
    __builtin_amdgcn_global_load_lds((const __attribute__((address_space(1))) void*)g,
                                     (__attribute__((address_space(3))) void*)l, 16, 0, 0);
}

// ================= prep kernel: conversions + transposes + gemv + zero =================
struct CvtSeg { const float* src; u16* dst; float* dstf; int n4; };
struct PrepArgs {
    CvtSeg s[9]; int total4;
    const float* Wv; u16* WvT;         // 768x768 transpose
    const float* ow; u16* owT;         // 512x512 transpose
    const float* Wo; const float* ob; const float* Wob; float* bo;
    float* sume;
};
#define PREP_CVT_BLKS 10320
#define TCVT0_BLKS 576
#define TCVT1_BLKS 256
#define GEMV_BLKS 192
#define ZERO_BLKS 16

__global__ __launch_bounds__(256, 8)
void prep_k(PrepArgs a){
    __shared__ float t[32][33];
    const int bid = blockIdx.x, tid = threadIdx.x;
    if (bid < PREP_CVT_BLKS){
        int i = bid*256 + tid;
        if (i >= a.total4) return;
        #pragma unroll
        for (int k=0;k<9;k++){
            if (i < a.s[k].n4){
                float4 v = *(const float4*)(a.s[k].src + (size_t)i*4);
                if (a.s[k].dstf) *(float4*)(a.s[k].dstf + (size_t)i*4) = v;
                ushort4 u; u.x=f2bf(v.x); u.y=f2bf(v.y); u.z=f2bf(v.z); u.w=f2bf(v.w);
                *(ushort4*)(a.s[k].dst + (size_t)i*4) = u;
                return;
            }
            i -= a.s[k].n4;
        }
        return;
    }
    int local = bid - PREP_CVT_BLKS;
    if (local < TCVT0_BLKS + TCVT1_BLKS){
        const float* in; u16* out; int R, bx, by;
        if (local < TCVT0_BLKS){ in=a.Wv; out=a.WvT; R=Nd; bx=local%24; by=local/24; }
        else { int l2=local-TCVT0_BLKS; in=a.ow; out=a.owT; R=Ed; bx=l2%16; by=l2/16; }
        const int tx = tid & 31, ty = tid >> 5;
        const int r0 = by*32, c0 = bx*32;
        #pragma unroll
        for (int i=0;i<4;i++)
            t[ty + i*8][tx] = in[(size_t)(r0+ty+i*8)*R + c0+tx];
        __syncthreads();
        #pragma unroll
        for (int i=0;i<4;i++)
            out[(size_t)(c0+ty+i*8)*R + r0+tx] = f2bf(t[tx][ty+i*8]);
        return;
    }
    local -= TCVT0_BLKS + TCVT1_BLKS;
    if (local < GEMV_BLKS){
        const int wave = tid >> 6, lane = tid & 63;
        const int i = local*4 + wave;
        float s = 0.f;
        for (int j = lane; j < 512; j += 64) s += a.Wo[(size_t)i*512 + j] * a.ob[j];
        #pragma unroll
        for (int off = 32; off; off >>= 1) s += __shfl_down(s, off);
        if (lane == 0) a.bo[i] = s + a.Wob[i];
        return;
    }
    local -= GEMV_BLKS;
    {
        int idx = local*1024 + tid*4;
        *(float4*)(a.sume + idx) = make_float4(0.f,0.f,0.f,0.f);
    }
}

// ================= batched GEMM: C[M,N] = alpha*A[M,K]@B[N,K]^T (+bias*bscale) =================
struct GSeg {
    const u16* A; const u16* B; void* C; const float* bias;
    int M, N, K; float alpha, bscale; int biasmode, outf32, blk0, nbx;
};
struct GBatch { GSeg s[5]; int nseg; };

__global__ __launch_bounds__(256, 3)
void gemm_multi(GBatch gb)
{
    __shared__ u16 lA[128*64];
    __shared__ u16 lB[128*64];
    const int bid = blockIdx.x;
    int si = 0;
    #pragma unroll
    for (int k=1;k<5;k++) if (k < gb.nseg && bid >= gb.s[k].blk0) si = k;
    const GSeg sg = gb.s[si];
    const int local = bid - sg.blk0;
    const int bx = local % sg.nbx, by = local / sg.nbx;
    const int K = sg.K, N = sg.N;

    const int tid = threadIdx.x;
    const int wave = tid >> 6, lane = tid & 63;
    const int wr = wave >> 1, wc = wave & 1;
    const size_t row0 = (size_t)by * 128;
    const size_t col0 = (size_t)bx * 128;

    f32x4 acc[4][4] = {};

    const int srow = wave*32 + (lane>>3);
    const int scol = (lane&7)*8;
    const u16* gA = sg.A + (row0 + srow)*(size_t)K + scol;
    const u16* gB = sg.B + (col0 + srow)*(size_t)K + scol;

    for (int kt = 0; kt < K; kt += 64) {
        #pragma unroll
        for (int i = 0; i < 4; ++i) {
            glds16(gA + (size_t)i*8*K + kt, lA + (wave*32 + i*8)*64);
            glds16(gB + (size_t)i*8*K + kt, lB + (wave*32 + i*8)*64);
        }
        __syncthreads();
        #pragma unroll
        for (int ks = 0; ks < 2; ++ks) {
            bf16x8 af[4], bfv[4];
            #pragma unroll
            for (int i = 0; i < 4; ++i)
                af[i] = *(const bf16x8*)&lA[(wr*64 + i*16 + (lane&15))*64 + ks*32 + (lane>>4)*8];
            #pragma unroll
            for (int i = 0; i < 4; ++i)
                bfv[i] = *(const bf16x8*)&lB[(wc*64 + i*16 + (lane&15))*64 + ks*32 + (lane>>4)*8];
            #pragma unroll
            for (int mi = 0; mi < 4; ++mi)
                #pragma unroll
                for (int ni = 0; ni < 4; ++ni)
                    acc[mi][ni] = __builtin_amdgcn_mfma_f32_16x16x32_bf16(af[mi], bfv[ni], acc[mi][ni], 0, 0, 0);
        }
        __syncthreads();
    }

    #pragma unroll
    for (int mi = 0; mi < 4; ++mi) {
        #pragma unroll
        for (int j = 0; j < 4; ++j) {
            const size_t r = row0 + wr*64 + mi*16 + (lane>>4)*4 + j;
            float badd_r = (sg.biasmode==2) ? sg.bias[r]*sg.bscale : 0.f;
            #pragma unroll
            for (int ni = 0; ni < 4; ++ni) {
                const size_t c = col0 + wc*64 + ni*16 + (lane&15);
                float bv = (sg.biasmode==1) ? sg.bias[c]*sg.bscale : badd_r;
                float v = acc[mi][ni][j] * sg.alpha + bv;
                if (sg.outf32) ((float*)sg.C)[r*(size_t)N + c] = v;
                else           ((u16*)sg.C)[r*(size_t)N + c] = f2bf(v);
            }
        }
    }
}

// ================= fused attention: sumexp + unnormalized ctx partials =================
__global__ __launch_bounds__(256, 2)
void attn_sc(const u16* __restrict__ qp, const u16* __restrict__ kp,
             const u16* __restrict__ vTp, float* __restrict__ sumexp,
             u16* __restrict__ part)
{
    __shared__ u16 lK[2][64*64];
    __shared__ u16 lV[2][64*64];
    __shared__ u16 lP[4][64*64];
    const int tid = threadIdx.x, w = tid>>6, l = tid&63;
    const int g = l>>4, b15 = l&15;
    const int h = blockIdx.x & 7;
    const int rest = blockIdx.x >> 3;
    const int msl = rest & (NSL-1), bt = rest >> 3;
    const int m0 = msl * (AIT*64);

    bf16x8 qf[4][2];
    #pragma unroll
    for (int rt=0; rt<4; ++rt)
        #pragma unroll
        for (int ks=0; ks<2; ++ks)
            qf[rt][ks] = *(const bf16x8*)&qp[(size_t)(bt*256 + w*64 + rt*16 + b15)*512
                                            + h*64 + ks*32 + g*8];

    int addrW[4][4], addrR[4][2];
    #pragma unroll
    for (int rt=0; rt<4; ++rt){
        int bl = rt*16 + b15;
        #pragma unroll
        for (int ct=0; ct<4; ++ct){
            int chunk = ct*2 + (g>>1);
            addrW[rt][ct] = bl*128 + ((chunk ^ (bl&7))<<4) + (g&1)*8;
        }
        #pragma unroll
        for (int ks2=0; ks2<2; ++ks2)
            addrR[rt][ks2] = bl*128 + (((ks2*4+g) ^ (bl&7))<<4);
    }

    const int srcc = ((l&7) ^ (l>>3))*8;
    char* lPw = (char*)lP[w];

    auto STAGE = [&](int buf, int mb){
        #pragma unroll
        for (int i=0;i<2;i++)
            glds16(kp + (size_t)(mb + w*16 + i*8 + (l>>3))*512 + h*64 + srcc,
                   &lK[buf][(w*16 + i*8)*64]);
        #pragma unroll
        for (int i=0;i<2;i++)
            glds16(vTp + (size_t)(h*64 + w*16 + i*8 + (l>>3))*8192 + mb + srcc,
                   &lV[buf][(w*16 + i*8)*64]);
    };

    STAGE(0, m0);
    __syncthreads();

    f32x4 cacc[4][4] = {};
    float rs[4] = {};
    int cur = 0;
    for (int t=0; t<AIT; ++t){
        if (t+1 < AIT) STAGE(cur^1, m0 + (t+1)*64);

        f32x4 sacc[4][4] = {};
        #pragma unroll
        for (int ks=0; ks<2; ++ks){
            bf16x8 bk[4];
            #pragma unroll
            for (int ct=0; ct<4; ++ct)
                bk[ct] = *(const bf16x8*)&lK[cur][(ct*16+b15)*64 + (((ks*4+g) ^ (b15&7))<<3)];
            #pragma unroll
            for (int rt=0; rt<4; ++rt)
                #pragma unroll
                for (int ct=0; ct<4; ++ct)
                    sacc[rt][ct] = __builtin_amdgcn_mfma_f32_16x16x32_bf16(bk[ct], qf[rt][ks], sacc[rt][ct],0,0,0);
        }
        #pragma unroll
        for (int rt=0; rt<4; ++rt)
            #pragma unroll
            for (int ct=0; ct<4; ++ct){
                float p0 = fexp2(sacc[rt][ct][0]);
                float p1 = fexp2(sacc[rt][ct][1]);
                float p2 = fexp2(sacc[rt][ct][2]);
                float p3 = fexp2(sacc[rt][ct][3]);
                rs[rt] += (p0+p1)+(p2+p3);
                uint2 pk; pk.x = pack2(p0,p1); pk.y = pack2(p2,p3);
                *(uint2*)(lPw + addrW[rt][ct]) = pk;
            }
        #pragma unroll
        for (int ks2=0; ks2<2; ++ks2){
            bf16x8 vb[4];
            #pragma unroll
            for (int ai=0; ai<4; ++ai)
                vb[ai] = *(const bf16x8*)&lV[cur][(ai*16+b15)*64 + (((ks2*4+g) ^ (b15&7))<<3)];
            #pragma unroll
            for (int rt=0; rt<4; ++rt){
                bf16x8 pa = *(const bf16x8*)(lPw + addrR[rt][ks2]);
                #pragma unroll
                for (int ai=0; ai<4; ++ai)
                    cacc[rt][ai] = __builtin_amdgcn_mfma_f32_16x16x32_bf16(pa, vb[ai], cacc[rt][ai],0,0,0);
            }
        }
        __syncthreads();
        cur ^= 1;
    }

    #pragma unroll
    for (int rt=0; rt<4; ++rt)
        #pragma unroll
        for (int ai=0; ai<4; ++ai)
            #pragma unroll
            for (int j=0; j<4; ++j){
                size_t r = (size_t)bt*256 + w*64 + rt*16 + g*4 + j;
                size_t c = (size_t)h*64 + ai*16 + b15;
                part[((size_t)msl<<20) + r*512 + c] = f2bf(cacc[rt][ai][j]);
            }
    #pragma unroll
    for (int rt=0; rt<4; ++rt){
        float s = rs[rt];
        s += __shfl_xor(s, 16); s += __shfl_xor(s, 32);
        if (l < 16)
            atomicAdd(&sumexp[h*2048 + bt*256 + w*64 + rt*16 + l], s);
    }
}

// ctx[b,e] = (sum_msl part[msl][b][e]) / sumexp[h(e), b]
__global__ void ctx_reduce_k(const u16* __restrict__ part, const float* __restrict__ sume,
                             u16* __restrict__ ctx){
    int i = (blockIdx.x*256 + threadIdx.x)*4;
    int b = i >> 9, h = (i >> 6) & 7;
    float ri = 1.0f / sume[h*2048 + b];
    float s0=0.f, s1=0.f, s2=0.f, s3=0.f;
    #pragma unroll
    for (int k=0;k<NSL;k++){
        ushort4 v = *(const ushort4*)(part + ((size_t)k<<20) + i);
        s0 += bf2f(v.x); s1 += bf2f(v.y); s2 += bf2f(v.z); s3 += bf2f(v.w);
    }
    ushort4 u;
    u.x = f2bf(s0*ri); u.y = f2bf(s1*ri); u.z = f2bf(s2*ri); u.w = f2bf(s3*ri);
    *(ushort4*)(ctx + i) = u;
}

// ================= final merged kernel: epilogue GEMM (96 blocks) + attn_f (1024 blocks) =================
// attn_f v3: all-8-heads K in 64KB LDS (one barrier total), h as RUNTIME loop
// (#pragma unroll 1) so live ranges stay one-iteration wide (no spill, cf. R9/R10).
// + T5 s_setprio around the MFMA cluster (waves are phase-diverse: no in-loop barriers).
struct FinArgs {
    const u16* ctxb; const u16* Woo2T; const float* bo; float* out_xhat;
    const u16* qp; const u16* kp; const float* sume; float* fo;
};
#define EPB 96

__global__ __launch_bounds__(256, 2)
void fin_k(FinArgs fa)
{
    __shared__ char smem[73728];   // 72 KB
    const int tid = threadIdx.x;

    if (blockIdx.x < EPB){
        // ---- epilogue GEMM: out_xhat[2048,768] = ctxb[2048,512] @ Woo2T[768,512]^T + bo ----
        u16* lA = (u16*)smem;             // 128*64
        u16* lB = (u16*)(smem + 16384);   // 128*64
        const int local = blockIdx.x;
        const int bx = local % 6, by = local / 6;
        const int K = Ed, N = Nd;
        const int wave = tid >> 6, lane = tid & 63;
        const int wr = wave >> 1, wc = wave & 1;
        const size_t row0 = (size_t)by * 128;
        const size_t col0 = (size_t)bx * 128;
        f32x4 acc[4][4] = {};
        const int srow = wave*32 + (lane>>3);
        const int scol = (lane&7)*8;
        const u16* gA = fa.ctxb + (row0 + srow)*(size_t)K + scol;
        const u16* gB = fa.Woo2T + (col0 + srow)*(size_t)K + scol;
        for (int kt = 0; kt < K; kt += 64) {
            #pragma unroll
            for (int i = 0; i < 4; ++i) {
                glds16(gA + (size_t)i*8*K + kt, lA + (wave*32 + i*8)*64);
                glds16(gB + (size_t)i*8*K + kt, lB + (wave*32 + i*8)*64);
            }
            __syncthreads();
            #pragma unroll
            for (int ks = 0; ks < 2; ++ks) {
                bf16x8 af[4], bfv[4];
                #pragma unroll
                for (int i = 0; i < 4; ++i)
                    af[i] = *(const bf16x8*)&lA[(wr*64 + i*16 + (lane&15))*64 + ks*32 + (lane>>4)*8];
                #pragma unroll
                for (int i = 0; i < 4; ++i)
                    bfv[i] = *(const bf16x8*)&lB[(wc*64 + i*16 + (lane&15))*64 + ks*32 + (lane>>4)*8];
                #pragma unroll
                for (int mi = 0; mi < 4; ++mi)
                    #pragma unroll
                    for (int ni = 0; ni < 4; ++ni)
                        acc[mi][ni] = __builtin_amdgcn_mfma_f32_16x16x32_bf16(af[mi], bfv[ni], acc[mi][ni], 0, 0, 0);
            }
            __syncthreads();
        }
        #pragma unroll
        for (int mi = 0; mi < 4; ++mi)
            #pragma unroll
            for (int j = 0; j < 4; ++j) {
                const size_t r = row0 + wr*64 + mi*16 + (lane>>4)*4 + j;
                #pragma unroll
                for (int ni = 0; ni < 4; ++ni) {
                    const size_t c = col0 + wc*64 + ni*16 + (lane&15);
                    fa.out_xhat[r*(size_t)N + c] = acc[mi][ni][j] + fa.bo[c];
                }
            }
        return;
    }

    // ---- attn_f: f[b,m] = sum_h exp2(q.k) * 0.125/sumexp[h,b] ----
    u16* lK = (u16*)smem;                    // [64 rows][512 cols] swizzled (64 KB)
    float* lR = (float*)(smem + 65536);      // [8*256] (8 KB)
    const int w = tid>>6, l = tid&63;
    const int g = l>>4, b15 = l&15;
    const int bid = blockIdx.x - EPB;
    const int xcd = bid & 7, r2 = bid >> 3;
    const int mt = xcd*16 + (r2 & 15), bt = r2 >> 4;  // mt 0..127, bt 0..7

    #pragma unroll
    for (int i=0;i<8;i++){
        int id = i*256 + tid;
        lR[id] = 0.125f / fa.sume[(id>>8)*2048 + bt*256 + (id&255)];
    }
    // stage all 8 heads: 64 rows x 512 bf16; one glds16 stages one full row.
    // LDS chunk p of row r holds global chunk (p&56)|((p^r)&7)  [16B chunks]
    #pragma unroll
    for (int i=0;i<16;i++){
        int row = w*16 + i;
        int sc = (l & 56) | ((l ^ row) & 7);
        glds16(fa.kp + (size_t)(mt*64 + row)*512 + sc*8, lK + row*512);
    }
    __syncthreads();

    f32x4 facc[4][4] = {};
    const u16* qbase = fa.qp + (size_t)(bt*256 + w*64 + b15)*512 + g*8;

    #pragma unroll 1
    for (int h=0; h<8; ++h){
        bf16x8 qf[4][2];
        #pragma unroll
        for (int rt=0; rt<4; ++rt)
            #pragma unroll
            for (int ks=0; ks<2; ++ks)
                qf[rt][ks] = *(const bf16x8*)&qbase[(size_t)(rt*16)*512 + h*64 + ks*32];
        #pragma unroll
        for (int ch=0; ch<2; ++ch){
            f32x4 sacc[4][2] = {};
            __builtin_amdgcn_s_setprio(1);
            #pragma unroll
            for (int ks=0; ks<2; ++ks){
                bf16x8 bk[2];
                #pragma unroll
                for (int c2=0; c2<2; ++c2){
                    int rb = (ch*2+c2)*16 + b15;
                    int chunk = h*8 + (((ks*4+g) ^ (rb&7)));
                    bk[c2] = *(const bf16x8*)&lK[rb*512 + chunk*8];
                }
                #pragma unroll
                for (int rt=0; rt<4; ++rt)
                    #pragma unroll
                    for (int c2=0; c2<2; ++c2)
                        sacc[rt][c2] = __builtin_amdgcn_mfma_f32_16x16x32_bf16(bk[c2], qf[rt][ks], sacc[rt][c2],0,0,0);
            }
            __builtin_amdgcn_s_setprio(0);
            #pragma unroll
            for (int rt=0; rt<4; ++rt){
                float ri = lR[h*256 + w*64 + rt*16 + b15];
                #pragma unroll
                for (int c2=0; c2<2; ++c2)
                    #pragma unroll
                    for (int j=0;j<4;j++)
                        facc[rt][ch*2+c2][j] += fexp2(sacc[rt][c2][j]) * ri;
            }
        }
        __builtin_amdgcn_sched_barrier(0);
    }
    #pragma unroll
    for (int rt=0; rt<4; ++rt){
        size_t b = (size_t)bt*256 + w*64 + rt*16 + b15;
        #pragma unroll
        for (int ct=0; ct<4; ++ct)
            *(float4*)&fa.fo[b*8192 + mt*64 + ct*16 + g*4] = *(float4*)&facc[rt][ct];
    }
}

// ------------------------------------------------------------------
extern "C" void kernel_launch(void* const* d_in, const int* in_sizes, int n_in,
                              void* d_out, int out_size, void* d_ws, size_t ws_size,
                              hipStream_t stream)
{
    const float* x   = (const float*)d_in[0];
    const float* Xc  = (const float*)d_in[1];
    const float* Wq  = (const float*)d_in[2];
    const float* Wk  = (const float*)d_in[3];
    const float* Wv  = (const float*)d_in[4];
    const float* qw  = (const float*)d_in[5];
    const float* kw  = (const float*)d_in[6];
    const float* vw  = (const float*)d_in[7];
    const float* bq  = (const float*)d_in[8];
    const float* bk  = (const float*)d_in[9];
    const float* bv  = (const float*)d_in[10];
    const float* ow  = (const float*)d_in[11];
    const float* ob  = (const float*)d_in[12];
    const float* Wo  = (const float*)d_in[13];
    const float* Wob = (const float*)d_in[14];

    float* out_x    = (float*)d_out;
    float* out_xhat = out_x + (size_t)Bd*Nd;
    float* out_f    = out_xhat + (size_t)Bd*Nd;
    float* out_V    = out_f + (size_t)Bd*Md;

    char* wsb = (char*)d_ws;
    size_t off = 0;
    auto alloc = [&](size_t bytes) -> void* {
        void* p = wsb + off; off += (bytes + 255) & ~(size_t)255; return p;
    };
    u16* xb     = (u16*)alloc((size_t)Bd*Nd*2);
    u16* Xb     = (u16*)alloc((size_t)Md*Nd*2);
    u16* qwb    = (u16*)alloc((size_t)Ed*Ed*2);
    u16* kwb    = (u16*)alloc((size_t)Ed*Ed*2);
    u16* vwb    = (u16*)alloc((size_t)Ed*Nd*2);
    u16* Wqb    = (u16*)alloc((size_t)Nd*Ed*2);
    u16* Wkb    = (u16*)alloc((size_t)Nd*Ed*2);
    u16* Wvb    = (u16*)alloc((size_t)Nd*Nd*2);
    u16* WvTb   = (u16*)alloc((size_t)Nd*Nd*2);
    u16* Wo_b   = (u16*)alloc((size_t)Nd*Ed*2);
    u16* owTb   = (u16*)alloc((size_t)Ed*Ed*2);
    u16* WqqT   = (u16*)alloc((size_t)Ed*Nd*2);
    u16* WkkT   = (u16*)alloc((size_t)Ed*Nd*2);
    u16* WvvT   = (u16*)alloc((size_t)Ed*Nd*2);
    u16* Woo2T  = (u16*)alloc((size_t)Nd*Ed*2);
    float* bo   = (float*)alloc((size_t)Nd*4);
    u16* qb     = (u16*)alloc((size_t)Bd*Ed*2);
    u16* kb     = (u16*)alloc((size_t)Md*Ed*2);
    u16* vTb    = (u16*)alloc((size_t)Ed*Md*2);
    u16* ctxb   = (u16*)alloc((size_t)Bd*Ed*2);
    float* sume = (float*)alloc((size_t)Hd*Bd*4);
    u16* part   = (u16*)alloc((size_t)NSL*Bd*Ed*2);
    if (off > ws_size) return;

    const float LOG2E = 1.44269504f;

    // ---- launch 1: prep ----
    PrepArgs pa;
    pa.s[0] = { x,  xb,  out_x,   Bd*Nd/4 };
    pa.s[1] = { Xc, Xb,  nullptr, Md*Nd/4 };
    pa.s[2] = { qw, qwb, nullptr, Ed*Ed/4 };
    pa.s[3] = { kw, kwb, nullptr, Ed*Ed/4 };
    pa.s[4] = { vw, vwb, nullptr, Ed*Nd/4 };
    pa.s[5] = { Wq, Wqb, nullptr, Nd*Ed/4 };
    pa.s[6] = { Wk, Wkb, nullptr, Nd*Ed/4 };
    pa.s[7] = { Wv, Wvb, nullptr, Nd*Nd/4 };
    pa.s[8] = { Wo, Wo_b, nullptr, Nd*Ed/4 };
    pa.total4 = (Bd*Nd + Md*Nd + Ed*Ed*2 + Ed*Nd + Nd*Ed*2 + Nd*Nd + Nd*Ed)/4;
    pa.Wv = Wv; pa.WvT = WvTb; pa.ow = ow; pa.owT = owTb;
    pa.Wo = Wo; pa.ob = ob; pa.Wob = Wob; pa.bo = bo;
    pa.sume = sume;
    prep_k<<<PREP_CVT_BLKS + TCVT0_BLKS + TCVT1_BLKS + GEMV_BLKS + ZERO_BLKS, 256, 0, stream>>>(pa);

    // ---- launch 2: batch1 = 4 weight combines + V projection (R14 split) ----
    {
        GBatch gb; gb.nseg = 5;
        gb.s[0] = { qwb, Wqb, WqqT, nullptr, Ed, Nd, Ed, 0.125f*0.125f*LOG2E, 1.f, 0, 0,   0, Nd/128 };
        gb.s[1] = { kwb, Wkb, WkkT, nullptr, Ed, Nd, Ed, 1.f, 1.f, 0, 0,  24, Nd/128 };
        gb.s[2] = { vwb, Wvb, WvvT, nullptr, Ed, Nd, Nd, 1.f, 1.f, 0, 0,  48, Nd/128 };
        gb.s[3] = { Wo_b, owTb, Woo2T, nullptr, Nd, Ed, Ed, 1.f, 1.f, 0, 0,  72, Ed/128 };
        gb.s[4] = { Xb, WvTb, out_V, nullptr, Md, Nd, Nd, 1.f, 1.f, 0, 1,  96, Nd/128 };
        gemm_multi<<<96 + (Md/128)*(Nd/128), 256, 0, stream>>>(gb);
    }
    // ---- launch 3: batch2 = q, k, vT projections (R14 split) ----
    {
        GBatch gb; gb.nseg = 3;
        gb.s[0] = { xb, WqqT, qb, bq, Bd, Ed, Nd, 1.f, 0.125f*LOG2E, 1, 0,   0, Ed/128 };
        gb.s[1] = { Xb, WkkT, kb, bk, Md, Ed, Nd, 1.f, 1.f, 1, 0,  64, Ed/128 };
        gb.s[2] = { WvvT, Xb, vTb, bv, Ed, Md, Nd, 1.f, 1.f, 2, 0, 320, Md/128 };
        gb.s[3] = gb.s[0]; gb.s[4] = gb.s[0];
        gemm_multi<<<320 + (Ed/128)*(Md/128), 256, 0, stream>>>(gb);
    }

    // ---- launch 4: fused attention (sumexp + ctx partials) ----
    attn_sc<<<512, 256, 0, stream>>>(qb, kb, vTb, sume, part);
    // ---- launch 5: ctx reduce ----
    ctx_reduce_k<<<Bd*Ed/1024, 256, 0, stream>>>(part, sume, ctxb);
    // ---- launch 6: merged epilogue GEMM + attn_f ----
    FinArgs fa = { ctxb, Woo2T, bo, out_xhat, qb, kb, sume, out_f };
    fin_k<<<EPB + 1024, 256, 0, stream>>>(fa);
}

// Round 17
// 175.873 us; speedup vs baseline: 1.0848x; 1.0132x over previous
//
#include <hip/hip_runtime.h>
#include <hip/hip_bf16.h>

typedef unsigned short u16;
typedef unsigned int u32;
typedef __attribute__((ext_vector_type(8))) __bf16 bf16x8;
typedef __attribute__((ext_vector_type(4))) float f32x4;

// dims
#define Bd  2048
#define Nd  768
#define Md  8192
#define Ed  512
#define Hd  8
#define NSL 8          // m-slices for ctx partials
#define AIT 16         // iters per attn_sc block = (Md/NSL)/64

__device__ __forceinline__ u16 f2bf(float f){
    union { __bf16 b; u16 u; } c; c.b = (__bf16)f; return c.u;
}
__device__ __forceinline__ float bf2f(u16 u){
    union { unsigned u; float f; } a; a.u = ((unsigned)u)<<16; return a.f;
}
__device__ __forceinline__ u32 pack2(float a, float b){
    union { ushort2 s; u32 u; } r;
    r.s.x = f2bf(a); r.s.y = f2bf(b);
    return r.u;
}
__device__ __forceinline__ float fexp2(float x){ return __builtin_amdgcn_exp2f(x); }

__device__ __forceinline__ void glds16(const void* g, void* l){
    __builtin_amdgcn_global_load_lds((const __attribute__((address_space(1))) void*)g,
                                     (__attribute__((address_space(3))) void*)l, 16, 0, 0);
}

// ================= prep kernel: conversions + transposes + gemv + zero =================
struct CvtSeg { const float* src; u16* dst; float* dstf; int n4; };
struct PrepArgs {
    CvtSeg s[9]; int total4;
    const float* Wv; u16* WvT;         // 768x768 transpose
    const float* ow; u16* owT;         // 512x512 transpose
    const float* Wo; const float* ob; const float* Wob; float* bo;
    float* sume;
};
#define PREP_CVT_BLKS 10320
#define TCVT0_BLKS 576
#define TCVT1_BLKS 256
#define GEMV_BLKS 192
#define ZERO_BLKS 16

__global__ __launch_bounds__(256, 8)
void prep_k(PrepArgs a){
    __shared__ float t[32][33];
    const int bid = blockIdx.x, tid = threadIdx.x;
    if (bid < PREP_CVT_BLKS){
        int i = bid*256 + tid;
        if (i >= a.total4) return;
        #pragma unroll
        for (int k=0;k<9;k++){
            if (i < a.s[k].n4){
                float4 v = *(const float4*)(a.s[k].src + (size_t)i*4);
                if (a.s[k].dstf) *(float4*)(a.s[k].dstf + (size_t)i*4) = v;
                ushort4 u; u.x=f2bf(v.x); u.y=f2bf(v.y); u.z=f2bf(v.z); u.w=f2bf(v.w);
                *(ushort4*)(a.s[k].dst + (size_t)i*4) = u;
                return;
            }
            i -= a.s[k].n4;
        }
        return;
    }
    int local = bid - PREP_CVT_BLKS;
    if (local < TCVT0_BLKS + TCVT1_BLKS){
        const float* in; u16* out; int R, bx, by;
        if (local < TCVT0_BLKS){ in=a.Wv; out=a.WvT; R=Nd; bx=local%24; by=local/24; }
        else { int l2=local-TCVT0_BLKS; in=a.ow; out=a.owT; R=Ed; bx=l2%16; by=l2/16; }
        const int tx = tid & 31, ty = tid >> 5;
        const int r0 = by*32, c0 = bx*32;
        #pragma unroll
        for (int i=0;i<4;i++)
            t[ty + i*8][tx] = in[(size_t)(r0+ty+i*8)*R + c0+tx];
        __syncthreads();
        #pragma unroll
        for (int i=0;i<4;i++)
            out[(size_t)(c0+ty+i*8)*R + r0+tx] = f2bf(t[tx][ty+i*8]);
        return;
    }
    local -= TCVT0_BLKS + TCVT1_BLKS;
    if (local < GEMV_BLKS){
        const int wave = tid >> 6, lane = tid & 63;
        const int i = local*4 + wave;
        float s = 0.f;
        for (int j = lane; j < 512; j += 64) s += a.Wo[(size_t)i*512 + j] * a.ob[j];
        #pragma unroll
        for (int off = 32; off; off >>= 1) s += __shfl_down(s, off);
        if (lane == 0) a.bo[i] = s + a.Wob[i];
        return;
    }
    local -= GEMV_BLKS;
    {
        int idx = local*1024 + tid*4;
        *(float4*)(a.sume + idx) = make_float4(0.f,0.f,0.f,0.f);
    }
}

// ================= batched GEMM: C[M,N] = alpha*A[M,K]@B[N,K]^T (+bias*bscale) =================
struct GSeg {
    const u16* A; const u16* B; void* C; const float* bias;
    int M, N, K; float alpha, bscale; int biasmode, outf32, blk0, nbx;
};
struct GBatch { GSeg s[5]; int nseg; };

__global__ __launch_bounds__(256, 3)
void gemm_multi(GBatch gb)
{
    __shared__ u16 lA[128*64];
    __shared__ u16 lB[128*64];
    const int bid = blockIdx.x;
    int si = 0;
    #pragma unroll
    for (int k=1;k<5;k++) if (k < gb.nseg && bid >= gb.s[k].blk0) si = k;
    const GSeg sg = gb.s[si];
    const int local = bid - sg.blk0;
    const int bx = local % sg.nbx, by = local / sg.nbx;
    const int K = sg.K, N = sg.N;

    const int tid = threadIdx.x;
    const int wave = tid >> 6, lane = tid & 63;
    const int wr = wave >> 1, wc = wave & 1;
    const size_t row0 = (size_t)by * 128;
    const size_t col0 = (size_t)bx * 128;

    f32x4 acc[4][4] = {};

    const int srow = wave*32 + (lane>>3);
    const int scol = (lane&7)*8;
    const u16* gA = sg.A + (row0 + srow)*(size_t)K + scol;
    const u16* gB = sg.B + (col0 + srow)*(size_t)K + scol;

    for (int kt = 0; kt < K; kt += 64) {
        #pragma unroll
        for (int i = 0; i < 4; ++i) {
            glds16(gA + (size_t)i*8*K + kt, lA + (wave*32 + i*8)*64);
            glds16(gB + (size_t)i*8*K + kt, lB + (wave*32 + i*8)*64);
        }
        __syncthreads();
        #pragma unroll
        for (int ks = 0; ks < 2; ++ks) {
            bf16x8 af[4], bfv[4];
            #pragma unroll
            for (int i = 0; i < 4; ++i)
                af[i] = *(const bf16x8*)&lA[(wr*64 + i*16 + (lane&15))*64 + ks*32 + (lane>>4)*8];
            #pragma unroll
            for (int i = 0; i < 4; ++i)
                bfv[i] = *(const bf16x8*)&lB[(wc*64 + i*16 + (lane&15))*64 + ks*32 + (lane>>4)*8];
            #pragma unroll
            for (int mi = 0; mi < 4; ++mi)
                #pragma unroll
                for (int ni = 0; ni < 4; ++ni)
                    acc[mi][ni] = __builtin_amdgcn_mfma_f32_16x16x32_bf16(af[mi], bfv[ni], acc[mi][ni], 0, 0, 0);
        }
        __syncthreads();
    }

    #pragma unroll
    for (int mi = 0; mi < 4; ++mi) {
        #pragma unroll
        for (int j = 0; j < 4; ++j) {
            const size_t r = row0 + wr*64 + mi*16 + (lane>>4)*4 + j;
            float badd_r = (sg.biasmode==2) ? sg.bias[r]*sg.bscale : 0.f;
            #pragma unroll
            for (int ni = 0; ni < 4; ++ni) {
                const size_t c = col0 + wc*64 + ni*16 + (lane&15);
                float bv = (sg.biasmode==1) ? sg.bias[c]*sg.bscale : badd_r;
                float v = acc[mi][ni][j] * sg.alpha + bv;
                if (sg.outf32) ((float*)sg.C)[r*(size_t)N + c] = v;
                else           ((u16*)sg.C)[r*(size_t)N + c] = f2bf(v);
            }
        }
    }
}

// ================= fused attention: sumexp + unnormalized ctx partials =================
__global__ __launch_bounds__(256, 2)
void attn_sc(const u16* __restrict__ qp, const u16* __restrict__ kp,
             const u16* __restrict__ vTp, float* __restrict__ sumexp,
             u16* __restrict__ part)
{
    __shared__ u16 lK[2][64*64];
    __shared__ u16 lV[2][64*64];
    __shared__ u16 lP[4][64*64];
    const int tid = threadIdx.x, w = tid>>6, l = tid&63;
    const int g = l>>4, b15 = l&15;
    const int h = blockIdx.x & 7;
    const int rest = blockIdx.x >> 3;
    const int msl = rest & (NSL-1), bt = rest >> 3;
    const int m0 = msl * (AIT*64);

    bf16x8 qf[4][2];
    #pragma unroll
    for (int rt=0; rt<4; ++rt)
        #pragma unroll
        for (int ks=0; ks<2; ++ks)
            qf[rt][ks] = *(const bf16x8*)&qp[(size_t)(bt*256 + w*64 + rt*16 + b15)*512
                                            + h*64 + ks*32 + g*8];

    int addrW[4][4], addrR[4][2];
    #pragma unroll
    for (int rt=0; rt<4; ++rt){
        int bl = rt*16 + b15;
        #pragma unroll
        for (int ct=0; ct<4; ++ct){
            int chunk = ct*2 + (g>>1);
            addrW[rt][ct] = bl*128 + ((chunk ^ (bl&7))<<4) + (g&1)*8;
        }
        #pragma unroll
        for (int ks2=0; ks2<2; ++ks2)
            addrR[rt][ks2] = bl*128 + (((ks2*4+g) ^ (bl&7))<<4);
    }

    const int srcc = ((l&7) ^ (l>>3))*8;
    char* lPw = (char*)lP[w];

    auto STAGE = [&](int buf, int mb){
        #pragma unroll
        for (int i=0;i<2;i++)
            glds16(kp + (size_t)(mb + w*16 + i*8 + (l>>3))*512 + h*64 + srcc,
                   &lK[buf][(w*16 + i*8)*64]);
        #pragma unroll
        for (int i=0;i<2;i++)
            glds16(vTp + (size_t)(h*64 + w*16 + i*8 + (l>>3))*8192 + mb + srcc,
                   &lV[buf][(w*16 + i*8)*64]);
    };

    STAGE(0, m0);
    __syncthreads();

    f32x4 cacc[4][4] = {};
    float rs[4] = {};
    int cur = 0;
    for (int t=0; t<AIT; ++t){
        if (t+1 < AIT) STAGE(cur^1, m0 + (t+1)*64);

        f32x4 sacc[4][4] = {};
        #pragma unroll
        for (int ks=0; ks<2; ++ks){
            bf16x8 bk[4];
            #pragma unroll
            for (int ct=0; ct<4; ++ct)
                bk[ct] = *(const bf16x8*)&lK[cur][(ct*16+b15)*64 + (((ks*4+g) ^ (b15&7))<<3)];
            #pragma unroll
            for (int rt=0; rt<4; ++rt)
                #pragma unroll
                for (int ct=0; ct<4; ++ct)
                    sacc[rt][ct] = __builtin_amdgcn_mfma_f32_16x16x32_bf16(bk[ct], qf[rt][ks], sacc[rt][ct],0,0,0);
        }
        #pragma unroll
        for (int rt=0; rt<4; ++rt)
            #pragma unroll
            for (int ct=0; ct<4; ++ct){
                float p0 = fexp2(sacc[rt][ct][0]);
                float p1 = fexp2(sacc[rt][ct][1]);
                float p2 = fexp2(sacc[rt][ct][2]);
                float p3 = fexp2(sacc[rt][ct][3]);
                rs[rt] += (p0+p1)+(p2+p3);
                uint2 pk; pk.x = pack2(p0,p1); pk.y = pack2(p2,p3);
                *(uint2*)(lPw + addrW[rt][ct]) = pk;
            }
        #pragma unroll
        for (int ks2=0; ks2<2; ++ks2){
            bf16x8 vb[4];
            #pragma unroll
            for (int ai=0; ai<4; ++ai)
                vb[ai] = *(const bf16x8*)&lV[cur][(ai*16+b15)*64 + (((ks2*4+g) ^ (b15&7))<<3)];
            #pragma unroll
            for (int rt=0; rt<4; ++rt){
                bf16x8 pa = *(const bf16x8*)(lPw + addrR[rt][ks2]);
                #pragma unroll
                for (int ai=0; ai<4; ++ai)
                    cacc[rt][ai] = __builtin_amdgcn_mfma_f32_16x16x32_bf16(pa, vb[ai], cacc[rt][ai],0,0,0);
            }
        }
        __syncthreads();
        cur ^= 1;
    }

    #pragma unroll
    for (int rt=0; rt<4; ++rt)
        #pragma unroll
        for (int ai=0; ai<4; ++ai)
            #pragma unroll
            for (int j=0; j<4; ++j){
                size_t r = (size_t)bt*256 + w*64 + rt*16 + g*4 + j;
                size_t c = (size_t)h*64 + ai*16 + b15;
                part[((size_t)msl<<20) + r*512 + c] = f2bf(cacc[rt][ai][j]);
            }
    #pragma unroll
    for (int rt=0; rt<4; ++rt){
        float s = rs[rt];
        s += __shfl_xor(s, 16); s += __shfl_xor(s, 32);
        if (l < 16)
            atomicAdd(&sumexp[h*2048 + bt*256 + w*64 + rt*16 + l], s);
    }
}

// ctx[b,e] = (sum_msl part[msl][b][e]) / sumexp[h(e), b]
__global__ void ctx_reduce_k(const u16* __restrict__ part, const float* __restrict__ sume,
                             u16* __restrict__ ctx){
    int i = (blockIdx.x*256 + threadIdx.x)*4;
    int b = i >> 9, h = (i >> 6) & 7;
    float ri = 1.0f / sume[h*2048 + b];
    float s0=0.f, s1=0.f, s2=0.f, s3=0.f;
    #pragma unroll
    for (int k=0;k<NSL;k++){
        ushort4 v = *(const ushort4*)(part + ((size_t)k<<20) + i);
        s0 += bf2f(v.x); s1 += bf2f(v.y); s2 += bf2f(v.z); s3 += bf2f(v.w);
    }
    ushort4 u;
    u.x = f2bf(s0*ri); u.y = f2bf(s1*ri); u.z = f2bf(s2*ri); u.w = f2bf(s3*ri);
    *(ushort4*)(ctx + i) = u;
}

// ================= final merged kernel: epilogue GEMM (96 blocks) + attn_f (1024 blocks) =================
// attn_f v3: all-8-heads K in 64KB LDS (one barrier total), h as RUNTIME loop
// (#pragma unroll 1) so live ranges stay one-iteration wide (no spill, cf. R9/R10).
struct FinArgs {
    const u16* ctxb; const u16* Woo2T; const float* bo; float* out_xhat;
    const u16* qp; const u16* kp; const float* sume; float* fo;
};
#define EPB 96

__global__ __launch_bounds__(256, 2)
void fin_k(FinArgs fa)
{
    __shared__ char smem[73728];   // 72 KB
    const int tid = threadIdx.x;

    if (blockIdx.x < EPB){
        // ---- epilogue GEMM: out_xhat[2048,768] = ctxb[2048,512] @ Woo2T[768,512]^T + bo ----
        u16* lA = (u16*)smem;             // 128*64
        u16* lB = (u16*)(smem + 16384);   // 128*64
        const int local = blockIdx.x;
        const int bx = local % 6, by = local / 6;
        const int K = Ed, N = Nd;
        const int wave = tid >> 6, lane = tid & 63;
        const int wr = wave >> 1, wc = wave & 1;
        const size_t row0 = (size_t)by * 128;
        const size_t col0 = (size_t)bx * 128;
        f32x4 acc[4][4] = {};
        const int srow = wave*32 + (lane>>3);
        const int scol = (lane&7)*8;
        const u16* gA = fa.ctxb + (row0 + srow)*(size_t)K + scol;
        const u16* gB = fa.Woo2T + (col0 + srow)*(size_t)K + scol;
        for (int kt = 0; kt < K; kt += 64) {
            #pragma unroll
            for (int i = 0; i < 4; ++i) {
                glds16(gA + (size_t)i*8*K + kt, lA + (wave*32 + i*8)*64);
                glds16(gB + (size_t)i*8*K + kt, lB + (wave*32 + i*8)*64);
            }
            __syncthreads();
            #pragma unroll
            for (int ks = 0; ks < 2; ++ks) {
                bf16x8 af[4], bfv[4];
                #pragma unroll
                for (int i = 0; i < 4; ++i)
                    af[i] = *(const bf16x8*)&lA[(wr*64 + i*16 + (lane&15))*64 + ks*32 + (lane>>4)*8];
                #pragma unroll
                for (int i = 0; i < 4; ++i)
                    bfv[i] = *(const bf16x8*)&lB[(wc*64 + i*16 + (lane&15))*64 + ks*32 + (lane>>4)*8];
                #pragma unroll
                for (int mi = 0; mi < 4; ++mi)
                    #pragma unroll
                    for (int ni = 0; ni < 4; ++ni)
                        acc[mi][ni] = __builtin_amdgcn_mfma_f32_16x16x32_bf16(af[mi], bfv[ni], acc[mi][ni], 0, 0, 0);
            }
            __syncthreads();
        }
        #pragma unroll
        for (int mi = 0; mi < 4; ++mi)
            #pragma unroll
            for (int j = 0; j < 4; ++j) {
                const size_t r = row0 + wr*64 + mi*16 + (lane>>4)*4 + j;
                #pragma unroll
                for (int ni = 0; ni < 4; ++ni) {
                    const size_t c = col0 + wc*64 + ni*16 + (lane&15);
                    fa.out_xhat[r*(size_t)N + c] = acc[mi][ni][j] + fa.bo[c];
                }
            }
        return;
    }

    // ---- attn_f: f[b,m] = sum_h exp2(q.k) * 0.125/sumexp[h,b] ----
    u16* lK = (u16*)smem;                    // [64 rows][512 cols] swizzled (64 KB)
    float* lR = (float*)(smem + 65536);      // [8*256] (8 KB)
    const int w = tid>>6, l = tid&63;
    const int g = l>>4, b15 = l&15;
    const int bid = blockIdx.x - EPB;
    const int xcd = bid & 7, r2 = bid >> 3;
    const int mt = xcd*16 + (r2 & 15), bt = r2 >> 4;  // mt 0..127, bt 0..7

    #pragma unroll
    for (int i=0;i<8;i++){
        int id = i*256 + tid;
        lR[id] = 0.125f / fa.sume[(id>>8)*2048 + bt*256 + (id&255)];
    }
    // stage all 8 heads: 64 rows x 512 bf16; one glds16 stages one full row.
    // LDS chunk p of row r holds global chunk (p&56)|((p^r)&7)  [16B chunks]
    #pragma unroll
    for (int i=0;i<16;i++){
        int row = w*16 + i;
        int sc = (l & 56) | ((l ^ row) & 7);
        glds16(fa.kp + (size_t)(mt*64 + row)*512 + sc*8, lK + row*512);
    }
    __syncthreads();

    f32x4 facc[4][4] = {};
    const u16* qbase = fa.qp + (size_t)(bt*256 + w*64 + b15)*512 + g*8;

    #pragma unroll 1
    for (int h=0; h<8; ++h){
        bf16x8 qf[4][2];
        #pragma unroll
        for (int rt=0; rt<4; ++rt)
            #pragma unroll
            for (int ks=0; ks<2; ++ks)
                qf[rt][ks] = *(const bf16x8*)&qbase[(size_t)(rt*16)*512 + h*64 + ks*32];
        #pragma unroll
        for (int ch=0; ch<2; ++ch){
            f32x4 sacc[4][2] = {};
            #pragma unroll
            for (int ks=0; ks<2; ++ks){
                bf16x8 bk[2];
                #pragma unroll
                for (int c2=0; c2<2; ++c2){
                    int rb = (ch*2+c2)*16 + b15;
                    int chunk = h*8 + (((ks*4+g) ^ (rb&7)));
                    bk[c2] = *(const bf16x8*)&lK[rb*512 + chunk*8];
                }
                #pragma unroll
                for (int rt=0; rt<4; ++rt)
                    #pragma unroll
                    for (int c2=0; c2<2; ++c2)
                        sacc[rt][c2] = __builtin_amdgcn_mfma_f32_16x16x32_bf16(bk[c2], qf[rt][ks], sacc[rt][c2],0,0,0);
            }
            #pragma unroll
            for (int rt=0; rt<4; ++rt){
                float ri = lR[h*256 + w*64 + rt*16 + b15];
                #pragma unroll
                for (int c2=0; c2<2; ++c2)
                    #pragma unroll
                    for (int j=0;j<4;j++)
                        facc[rt][ch*2+c2][j] += fexp2(sacc[rt][c2][j]) * ri;
            }
        }
        __builtin_amdgcn_sched_barrier(0);
    }
    #pragma unroll
    for (int rt=0; rt<4; ++rt){
        size_t b = (size_t)bt*256 + w*64 + rt*16 + b15;
        #pragma unroll
        for (int ct=0; ct<4; ++ct)
            *(float4*)&fa.fo[b*8192 + mt*64 + ct*16 + g*4] = *(float4*)&facc[rt][ct];
    }
}

// ------------------------------------------------------------------
extern "C" void kernel_launch(void* const* d_in, const int* in_sizes, int n_in,
                              void* d_out, int out_size, void* d_ws, size_t ws_size,
                              hipStream_t stream)
{
    const float* x   = (const float*)d_in[0];
    const float* Xc  = (const float*)d_in[1];
    const float* Wq  = (const float*)d_in[2];
    const float* Wk  = (const float*)d_in[3];
    const float* Wv  = (const float*)d_in[4];
    const float* qw  = (const float*)d_in[5];
    const float* kw  = (const float*)d_in[6];
    const float* vw  = (const float*)d_in[7];
    const float* bq  = (const float*)d_in[8];
    const float* bk  = (const float*)d_in[9];
    const float* bv  = (const float*)d_in[10];
    const float* ow  = (const float*)d_in[11];
    const float* ob  = (const float*)d_in[12];
    const float* Wo  = (const float*)d_in[13];
    const float* Wob = (const float*)d_in[14];

    float* out_x    = (float*)d_out;
    float* out_xhat = out_x + (size_t)Bd*Nd;
    float* out_f    = out_xhat + (size_t)Bd*Nd;
    float* out_V    = out_f + (size_t)Bd*Md;

    char* wsb = (char*)d_ws;
    size_t off = 0;
    auto alloc = [&](size_t bytes) -> void* {
        void* p = wsb + off; off += (bytes + 255) & ~(size_t)255; return p;
    };
    u16* xb     = (u16*)alloc((size_t)Bd*Nd*2);
    u16* Xb     = (u16*)alloc((size_t)Md*Nd*2);
    u16* qwb    = (u16*)alloc((size_t)Ed*Ed*2);
    u16* kwb    = (u16*)alloc((size_t)Ed*Ed*2);
    u16* vwb    = (u16*)alloc((size_t)Ed*Nd*2);
    u16* Wqb    = (u16*)alloc((size_t)Nd*Ed*2);
    u16* Wkb    = (u16*)alloc((size_t)Nd*Ed*2);
    u16* Wvb    = (u16*)alloc((size_t)Nd*Nd*2);
    u16* WvTb   = (u16*)alloc((size_t)Nd*Nd*2);
    u16* Wo_b   = (u16*)alloc((size_t)Nd*Ed*2);
    u16* owTb   = (u16*)alloc((size_t)Ed*Ed*2);
    u16* WqqT   = (u16*)alloc((size_t)Ed*Nd*2);
    u16* WkkT   = (u16*)alloc((size_t)Ed*Nd*2);
    u16* WvvT   = (u16*)alloc((size_t)Ed*Nd*2);
    u16* Woo2T  = (u16*)alloc((size_t)Nd*Ed*2);
    float* bo   = (float*)alloc((size_t)Nd*4);
    u16* qb     = (u16*)alloc((size_t)Bd*Ed*2);
    u16* kb     = (u16*)alloc((size_t)Md*Ed*2);
    u16* vTb    = (u16*)alloc((size_t)Ed*Md*2);
    u16* ctxb   = (u16*)alloc((size_t)Bd*Ed*2);
    float* sume = (float*)alloc((size_t)Hd*Bd*4);
    u16* part   = (u16*)alloc((size_t)NSL*Bd*Ed*2);
    if (off > ws_size) return;

    const float LOG2E = 1.44269504f;

    // ---- launch 1: prep ----
    PrepArgs pa;
    pa.s[0] = { x,  xb,  out_x,   Bd*Nd/4 };
    pa.s[1] = { Xc, Xb,  nullptr, Md*Nd/4 };
    pa.s[2] = { qw, qwb, nullptr, Ed*Ed/4 };
    pa.s[3] = { kw, kwb, nullptr, Ed*Ed/4 };
    pa.s[4] = { vw, vwb, nullptr, Ed*Nd/4 };
    pa.s[5] = { Wq, Wqb, nullptr, Nd*Ed/4 };
    pa.s[6] = { Wk, Wkb, nullptr, Nd*Ed/4 };
    pa.s[7] = { Wv, Wvb, nullptr, Nd*Nd/4 };
    pa.s[8] = { Wo, Wo_b, nullptr, Nd*Ed/4 };
    pa.total4 = (Bd*Nd + Md*Nd + Ed*Ed*2 + Ed*Nd + Nd*Ed*2 + Nd*Nd + Nd*Ed)/4;
    pa.Wv = Wv; pa.WvT = WvTb; pa.ow = ow; pa.owT = owTb;
    pa.Wo = Wo; pa.ob = ob; pa.Wob = Wob; pa.bo = bo;
    pa.sume = sume;
    prep_k<<<PREP_CVT_BLKS + TCVT0_BLKS + TCVT1_BLKS + GEMV_BLKS + ZERO_BLKS, 256, 0, stream>>>(pa);

    // ---- launch 2: batch1 = 4 weight combines + V projection ----
    {
        GBatch gb; gb.nseg = 5;
        gb.s[0] = { qwb, Wqb, WqqT, nullptr, Ed, Nd, Ed, 0.125f*0.125f*LOG2E, 1.f, 0, 0,   0, Nd/128 };
        gb.s[1] = { kwb, Wkb, WkkT, nullptr, Ed, Nd, Ed, 1.f, 1.f, 0, 0,  24, Nd/128 };
        gb.s[2] = { vwb, Wvb, WvvT, nullptr, Ed, Nd, Nd, 1.f, 1.f, 0, 0,  48, Nd/128 };
        gb.s[3] = { Wo_b, owTb, Woo2T, nullptr, Nd, Ed, Ed, 1.f, 1.f, 0, 0,  72, Ed/128 };
        gb.s[4] = { Xb, WvTb, out_V, nullptr, Md, Nd, Nd, 1.f, 1.f, 0, 1,  96, Nd/128 };
        gemm_multi<<<96 + (Md/128)*(Nd/128), 256, 0, stream>>>(gb);
    }
    // ---- launch 3: batch2 = q, k, vT projections ----
    {
        GBatch gb; gb.nseg = 3;
        gb.s[0] = { xb, WqqT, qb, bq, Bd, Ed, Nd, 1.f, 0.125f*LOG2E, 1, 0,   0, Ed/128 };
        gb.s[1] = { Xb, WkkT, kb, bk, Md, Ed, Nd, 1.f, 1.f, 1, 0,  64, Ed/128 };
        gb.s[2] = { WvvT, Xb, vTb, bv, Ed, Md, Nd, 1.f, 1.f, 2, 0, 320, Md/128 };
        gb.s[3] = gb.s[0]; gb.s[4] = gb.s[0];
        gemm_multi<<<320 + (Ed/128)*(Md/128), 256, 0, stream>>>(gb);
    }

    // ---- launch 4: fused attention (sumexp + ctx partials) ----
    attn_sc<<<512, 256, 0, stream>>>(qb, kb, vTb, sume, part);
    // ---- launch 5: ctx reduce ----
    ctx_reduce_k<<<Bd*Ed/1024, 256, 0, stream>>>(part, sume, ctxb);
    // ---- launch 6: merged epilogue GEMM + attn_f ----
    FinArgs fa = { ctxb, Woo2T, bo, out_xhat, qb, kb, sume, out_f };
    fin_k<<<EPB + 1024, 256, 0, stream>>>(fa);
}